// Round 11
// baseline (111.985 us; speedup 1.0000x reference)
//
#include <hip/hip_runtime.h>
#include <hip/hip_bf16.h>

#define BATCH 1024
#define INPUT_DIM 1024
#define NBK 32
#define KDIM 16

typedef __attribute__((ext_vector_type(8))) short short8;
typedef __attribute__((ext_vector_type(4))) float f32x4;

// u16 quantization of act: u = round(act*QS) + 32768. Bias cancels in |a-c|;
// SAD accumulates integer L1; exp(-L1/QS) = exp2(L1_int * (-log2e/QS)).
#define QS 2048.0f
#define EXPC (-7.0444191e-4f)   // -log2(e)/2048

#if __has_builtin(__builtin_amdgcn_sad_u16)
__device__ __forceinline__ unsigned int sadu16(unsigned int a, unsigned int b,
                                               unsigned int acc) {
    return __builtin_amdgcn_sad_u16(a, b, acc);
}
#else
__device__ __forceinline__ unsigned int sadu16(unsigned int a, unsigned int b,
                                               unsigned int acc) {
    int d0 = (int)(a & 0xFFFFu) - (int)(b & 0xFFFFu);
    int d1 = (int)(a >> 16)     - (int)(b >> 16);
    return acc + (unsigned int)(d0 < 0 ? -d0 : d0) + (unsigned int)(d1 < 0 ? -d1 : d1);
}
#endif

// pack two fp32 -> one u32 holding two bf16 (truncation): 1 v_perm_b32.
__device__ __forceinline__ unsigned int pk_bf16_trunc(float lo, float hi) {
    union { float f; unsigned u; } a, b;
    a.f = lo; b.f = hi;
    return __builtin_amdgcn_perm(b.u, a.u, 0x07060302u);
}

// ---------------------------------------------------------------------------
// Kernel 1: act2u[k][b][m] (u16) via bf16 MFMA 16x16x32 — R9 VERBATIM
// (R10's W-LDS staging regressed: occupancy 8->4 blocks/CU cost more than
// the saved scalar loads). Direct fp32 reads + v_perm trunc-packs.
// Grid (k*32+btile)=1024 blocks x 256 thr; 4 waves split d 4-way, LDS reduce.
// Side job: each block copies a 4 KB slice of x -> out[b][0:1024].
// ---------------------------------------------------------------------------
__global__ __launch_bounds__(256) void gemm_k(const float* __restrict__ x,
                                              const float* __restrict__ W,
                                              unsigned short* __restrict__ act2u,
                                              float* __restrict__ out) {
    __shared__ float lds[1536];
    const int bid  = blockIdx.x;
    const int tid  = threadIdx.x;
    const int k    = bid >> 5;
    const int b0   = (bid & 31) * 32;
    const int lane = tid & 63;
    const int w4   = tid >> 6;                 // 0..3: d-quarter
    const int m16  = lane & 15;
    const int quad = lane >> 4;

    // side job: copy x slice into out (each block: 1024 floats, disjoint)
    {
        const int i = bid * 1024 + tid * 4;
        float4 v = *(const float4*)(x + i);
        const int b = i >> 10;
        const int d = i & 1023;
        *(float4*)(out + b * 1056 + d) = v;
    }

    const float* xa0 = x + (b0 + m16) * INPUT_DIM + w4 * 256 + quad * 8;
    const float* xa1 = xa0 + 16 * INPUT_DIM;
    const float* wb  = W + k * (INPUT_DIM * KDIM) + (w4 * 256 + quad * 8) * KDIM + m16;

    f32x4 acc0 = {0.f, 0.f, 0.f, 0.f};
    f32x4 acc1 = {0.f, 0.f, 0.f, 0.f};

#pragma unroll
    for (int s = 0; s < 8; ++s) {
        const float* pa0 = xa0 + s * 32;
        const float* pa1 = xa1 + s * 32;
        const float* pb  = wb + s * 32 * KDIM;
        float4 a0l = *(const float4*)(pa0);
        float4 a0h = *(const float4*)(pa0 + 4);
        float4 a1l = *(const float4*)(pa1);
        float4 a1h = *(const float4*)(pa1 + 4);
        float b0w = pb[0 * KDIM], b1w = pb[1 * KDIM];
        float b2w = pb[2 * KDIM], b3w = pb[3 * KDIM];
        float b4w = pb[4 * KDIM], b5w = pb[5 * KDIM];
        float b6w = pb[6 * KDIM], b7w = pb[7 * KDIM];
        union { unsigned int u[4]; short8 s8; } A0, A1, BV;
        A0.u[0] = pk_bf16_trunc(a0l.x, a0l.y); A0.u[1] = pk_bf16_trunc(a0l.z, a0l.w);
        A0.u[2] = pk_bf16_trunc(a0h.x, a0h.y); A0.u[3] = pk_bf16_trunc(a0h.z, a0h.w);
        A1.u[0] = pk_bf16_trunc(a1l.x, a1l.y); A1.u[1] = pk_bf16_trunc(a1l.z, a1l.w);
        A1.u[2] = pk_bf16_trunc(a1h.x, a1h.y); A1.u[3] = pk_bf16_trunc(a1h.z, a1h.w);
        BV.u[0] = pk_bf16_trunc(b0w, b1w);     BV.u[1] = pk_bf16_trunc(b2w, b3w);
        BV.u[2] = pk_bf16_trunc(b4w, b5w);     BV.u[3] = pk_bf16_trunc(b6w, b7w);
        acc0 = __builtin_amdgcn_mfma_f32_16x16x32_bf16(A0.s8, BV.s8, acc0, 0, 0, 0);
        acc1 = __builtin_amdgcn_mfma_f32_16x16x32_bf16(A1.s8, BV.s8, acc1, 0, 0, 0);
    }

    if (w4 > 0) {
        float* r = &lds[(w4 - 1) * 512 + lane * 8];
        *(float4*)(r)     = make_float4(acc0[0], acc0[1], acc0[2], acc0[3]);
        *(float4*)(r + 4) = make_float4(acc1[0], acc1[1], acc1[2], acc1[3]);
    }
    __syncthreads();
    if (w4 == 0) {
#pragma unroll
        for (int j = 0; j < 3; ++j) {
            const float* r = &lds[j * 512 + lane * 8];
            float4 p0 = *(const float4*)(r);
            float4 p1 = *(const float4*)(r + 4);
            acc0[0] += p0.x; acc0[1] += p0.y; acc0[2] += p0.z; acc0[3] += p0.w;
            acc1[0] += p1.x; acc1[1] += p1.y; acc1[2] += p1.z; acc1[3] += p1.w;
        }
        const int row0 = b0 + quad * 4;
#pragma unroll
        for (int r = 0; r < 4; ++r) {
            float q0 = fminf(fmaxf(acc0[r] * QS, -30000.f), 30000.f);
            float q1 = fminf(fmaxf(acc1[r] * QS, -30000.f), 30000.f);
            act2u[(k * BATCH + row0 + r) * KDIM + m16] =
                (unsigned short)(32768 + (int)rintf(q0));
            act2u[(k * BATCH + row0 + 16 + r) * KDIM + m16] =
                (unsigned short)(32768 + (int)rintf(q1));
        }
    }
}

// ---------------------------------------------------------------------------
// Kernel 2: pairwise v3 — 8 b-rows per thread (each c-row LDS read now feeds
// 8 features instead of 4; per-feature loop overhead halved; SAD count same).
// grid (cpair=32, k=32) = 1024 blocks x 256 thr. Block stages 32 c-rows
// (1 KB); tid>>7 selects which 16-c half this thread processes (per-wave
// uniform LDS addresses preserved). Partials -> 64 chunks, coalesced stores.
// ---------------------------------------------------------------------------
__global__ __launch_bounds__(256) void pairwise_k(const unsigned short* __restrict__ act2u,
                                                  float* __restrict__ part) {
    __shared__ unsigned int cs[32 * 8];  // 1 KB: 32 rows x 16 u16
    const int tid   = threadIdx.x;
    const int k     = blockIdx.y;
    const int cpair = blockIdx.x;
    const int chalf = tid >> 7;          // 0/1: which 16-c half
    const int bt    = tid & 127;
    const unsigned short* base = act2u + k * (BATCH * KDIM);

    if (tid < 64) ((uint4*)cs)[tid] = ((const uint4*)(base + cpair * 32 * KDIM))[tid];

    unsigned int a[8][8];
#pragma unroll
    for (int r = 0; r < 8; ++r) {
        const uint4* src = (const uint4*)(base + (bt + r * 128) * KDIM);
        uint4 u0 = src[0], u1 = src[1];
        a[r][0] = u0.x; a[r][1] = u0.y; a[r][2] = u0.z; a[r][3] = u0.w;
        a[r][4] = u1.x; a[r][5] = u1.y; a[r][6] = u1.z; a[r][7] = u1.w;
    }
    __syncthreads();

    float f[8] = {0.f, 0.f, 0.f, 0.f, 0.f, 0.f, 0.f, 0.f};
    const unsigned int* csh = cs + chalf * 16 * 8;
#pragma unroll 2
    for (int c = 0; c < 16; ++c) {
        uint4 q0 = *(const uint4*)&csh[c * 8];
        uint4 q1 = *(const uint4*)&csh[c * 8 + 4];
        unsigned int cr[8] = {q0.x, q0.y, q0.z, q0.w, q1.x, q1.y, q1.z, q1.w};
#pragma unroll
        for (int r = 0; r < 8; ++r) {
            unsigned int s = 0u;
#pragma unroll
            for (int j = 0; j < 8; ++j) s = sadu16(a[r][j], cr[j], s);
            f[r] += exp2f((float)s * EXPC);
        }
    }
    const int chunk = cpair * 2 + chalf;               // 0..63
    float* p = part + chunk * (NBK * BATCH) + k * BATCH + bt;
#pragma unroll
    for (int r = 0; r < 8; ++r) p[r * 128] = f[r];
}

// ---------------------------------------------------------------------------
// Kernel 3: out[b][1024+k] = sum over 64 chunks of part[ch][k][b].
// ---------------------------------------------------------------------------
__global__ __launch_bounds__(256) void combine_k(const float* __restrict__ part,
                                                 float* __restrict__ out) {
    const int t = blockIdx.x * 256 + threadIdx.x;   // k*1024 + b, t < 32768
    const int k = t >> 10;
    const int b = t & 1023;
    float s = 0.f;
#pragma unroll
    for (int i = 0; i < 64; ++i) s += part[i * (NBK * BATCH) + t];
    out[b * 1056 + 1024 + k] = s;
}

extern "C" void kernel_launch(void* const* d_in, const int* in_sizes, int n_in,
                              void* d_out, int out_size, void* d_ws, size_t ws_size,
                              hipStream_t stream) {
    const float* x = (const float*)d_in[0];
    const float* W = (const float*)d_in[1];
    float* out = (float*)d_out;

    unsigned short* act2u = (unsigned short*)d_ws;                  // 1 MB
    float* part = (float*)((char*)d_ws + 1024 * 1024);              // 8 MB

    gemm_k<<<1024, 256, 0, stream>>>(x, W, act2u, out);
    pairwise_k<<<dim3(32, 32), 256, 0, stream>>>(act2u, part);
    combine_k<<<128, 256, 0, stream>>>(part, out);
}